// Round 7
// baseline (98.959 us; speedup 1.0000x reference)
//
#include <hip/hip_runtime.h>

#define NLAT 361
#define NLON 720
#define LMAX 360
#define MMAX 361

#define TSTR 368                     // real table row stride (floats); cols 361..367 = 0
#define TAB_R_FLOATS (MMAX * TSTR)   // 132,848
#define XTQ_FLOATS (MMAX * NLAT * 8) // 1,042,568 per quarter (real Xt)

static constexpr double kPId = 3.14159265358979323846;
static constexpr float  kAngF = 8.72664625997164788e-3f;  // 2*pi/720

// ---------------- kernel 0a: real trig table Tc[m][n] ----------------
__global__ __launch_bounds__(256) void k_tables_r(float* __restrict__ tc) {
    int i = blockIdx.x * 256 + threadIdx.x;
    if (i >= TAB_R_FLOATS) return;
    int m = i / TSTR;
    int n = i - m * TSTR;
    float v = 0.f;
    if (n <= 360) {
        int t = (n * m) % NLON;
        float sn, cs;
        __sincosf((float)t * kAngF, &sn, &cs);
        float w = (n == 360) ? 0.5f : 1.0f;
        v = w * kAngF * cs;
    }
    tc[i] = v;
}

// ---------------- kernel 1: folded real DFT, n-split=4 ----------------
// Xq[nq][m,k,ch] = sum_{n in quarter nq} Tc[m][n] * xe[n,k,ch]
// block 256 = 2 kslots x 128 m-threads (3 m each); grid (181, 4).
__global__ __launch_bounds__(256) void k_dft_r(const float* __restrict__ x,
                                               const float* __restrict__ tc,
                                               float* __restrict__ xtq) {
    const int bx   = blockIdx.x;     // k pair
    const int nq   = blockIdx.y;     // n quarter
    const int tid  = threadIdx.x;
    const int tidm = tid & 127;
    const int ks   = tid >> 7;

    __shared__ __align__(16) float xr[2 * 8 * 724];
    __shared__ __align__(16) float xe[2 * 8 * TSTR];

    {   // stage raw x rows (coalesced float4), clamp k, zero pad [720..723]
        const float4* __restrict__ x4 = (const float4*)x;
        for (int j = tid; j < 2 * 8 * 180; j += 256) {
            int s  = j / 1440;
            int r  = j - s * 1440;
            int ch = r / 180;
            int q  = r - ch * 180;
            int k  = bx * 2 + s; int kv = (k <= 360) ? k : 360;
            ((float4*)&xr[(s * 8 + ch) * 724])[q] = x4[(ch * NLAT + kv) * 180 + q];
        }
        if (tid < 16) {
            int s = tid >> 3, ch = tid & 7;
            ((float4*)&xr[(s * 8 + ch) * 724])[180] = make_float4(0.f, 0.f, 0.f, 0.f);
        }
    }
    __syncthreads();

    // fold this quarter: xe[n] = x[n] + x[720-n]; n=0 uses pad(0); n>360 -> 0
    for (int j = tid; j < 2 * 8 * 92; j += 256) {
        int s  = j / 736;
        int r  = j - s * 736;
        int ch = r / 92;
        int nn = r - ch * 92;
        int n  = nq * 92 + nn;
        float v = 0.f;
        if (n <= 360) {
            float xa = xr[(s * 8 + ch) * 724 + n];
            float xb = xr[(s * 8 + ch) * 724 + (NLON - n)];
            v = xa + xb;
        }
        xe[(s * 8 + ch) * TSTR + n] = v;
    }
    __syncthreads();

    const int  m0  = tidm;
    const int  m1  = tidm + 128;
    const bool m2v = (tidm < 105);
    const int  m2  = m2v ? (tidm + 256) : 360;
    const float* __restrict__ t0 = tc + m0 * TSTR;
    const float* __restrict__ t1 = tc + m1 * TSTR;
    const float* __restrict__ t2 = tc + m2 * TSTR;
    const int qb = nq * 23;

    float a0[8], a1[8], a2[8];
#pragma unroll
    for (int b = 0; b < 8; ++b) { a0[b] = 0.f; a1[b] = 0.f; a2[b] = 0.f; }

    float4 f0 = *(const float4*)(t0 + 4 * qb);
    float4 f1 = *(const float4*)(t1 + 4 * qb);
    float4 f2 = *(const float4*)(t2 + 4 * qb);
    for (int it = 0; it < 23; ++it) {
        float4 g0, g1, g2;
        if (it < 22) {
            g0 = *(const float4*)(t0 + 4 * (qb + it + 1));
            g1 = *(const float4*)(t1 + 4 * (qb + it + 1));
            g2 = *(const float4*)(t2 + 4 * (qb + it + 1));
        }
        const float* __restrict__ xb = &xe[ks * 8 * TSTR + 4 * (qb + it)];
#pragma unroll
        for (int b = 0; b < 8; ++b) {
            float4 e = *(const float4*)(xb + b * TSTR);
            a0[b] += f0.x * e.x + f0.y * e.y + f0.z * e.z + f0.w * e.w;
            a1[b] += f1.x * e.x + f1.y * e.y + f1.z * e.z + f1.w * e.w;
            a2[b] += f2.x * e.x + f2.y * e.y + f2.z * e.z + f2.w * e.w;
        }
        if (it < 22) { f0 = g0; f1 = g1; f2 = g2; }
    }

    const int k = bx * 2 + ks;
    if (k <= 360) {
        // FIX (R6 bug): write into THIS quarter's buffer, not q0.
        float4* __restrict__ o4 = (float4*)(xtq + (size_t)nq * XTQ_FLOATS);
        int b0 = (m0 * NLAT + k) * 2;
        o4[b0]     = make_float4(a0[0], a0[1], a0[2], a0[3]);
        o4[b0 + 1] = make_float4(a0[4], a0[5], a0[6], a0[7]);
        int b1 = (m1 * NLAT + k) * 2;
        o4[b1]     = make_float4(a1[0], a1[1], a1[2], a1[3]);
        o4[b1 + 1] = make_float4(a1[4], a1[5], a1[6], a1[7]);
        if (m2v) {
            int b2 = (m2 * NLAT + k) * 2;
            o4[b2]     = make_float4(a2[0], a2[1], a2[2], a2[3]);
            o4[b2 + 1] = make_float4(a2[4], a2[5], a2[6], a2[7]);
        }
    }
}

// ---------------- kernel 1b: sum the 4 n-quarters ----------------
__global__ __launch_bounds__(256) void k_reduce(const float4* __restrict__ q0,
                                                const float4* __restrict__ q1,
                                                const float4* __restrict__ q2,
                                                const float4* __restrict__ q3,
                                                float4* __restrict__ o) {
    int i = blockIdx.x * 256 + threadIdx.x;
    if (i >= XTQ_FLOATS / 4) return;
    float4 a = q0[i], b = q1[i], c = q2[i], d = q3[i];
    o[i] = make_float4(a.x + b.x + c.x + d.x, a.y + b.y + c.y + d.y,
                       a.z + b.z + c.z + d.z, a.w + b.w + c.w + d.w);
}

// ---------------- legacy folded DFT (cplx hedge / small-ws fallback) ----------------
template<int CPLX>
__global__ __launch_bounds__(192) void k_dft_leg(const float* __restrict__ x,
                                                 float* __restrict__ xt,
                                                 int mb, int mc) {
    const int k    = blockIdx.x;
    const int half = blockIdx.y;
    const int tid  = threadIdx.x;

    __shared__ __align__(16) float  xr[8 * 724];
    __shared__ __align__(16) float2 exo[8 * 362];

    {
        const float4* __restrict__ x4 = (const float4*)x;
        for (int j = tid; j < 8 * 180; j += 192) {
            int b = j / 180, q = j - b * 180;
            ((float4*)&xr[b * 724])[q] = x4[(b * NLAT + k) * 180 + q];
        }
        if (tid < 8) ((float4*)&xr[tid * 724])[180] = make_float4(0.f, 0.f, 0.f, 0.f);
    }
    __syncthreads();

    for (int j = tid; j < 8 * NLAT; j += 192) {
        int b = j / NLAT, n = j - b * NLAT;
        float xa  = xr[b * 724 + n];
        float xbv = xr[b * 724 + (NLON - n)];
        exo[b * 362 + n] = make_float2(xa + xbv, xa - xbv);
    }
    __syncthreads();

    const int  m_local = half * 192 + tid;
    const bool valid   = (m_local < mc);
    const int  m       = mb + (valid ? m_local : 0);

    float aRe[8], aIm[8];
#pragma unroll
    for (int b = 0; b < 8; ++b) { aRe[b] = 0.f; aIm[b] = 0.f; }

    int tacc = 0;
    for (int n = 0; n < NLAT; ++n) {
        float sn, cs;
        __sincosf((float)tacc * kAngF, &sn, &cs);
        float wgt = (n == 360) ? 0.5f : 1.0f;
        float fc = wgt * kAngF * cs;
        float fs = -wgt * kAngF * sn;
        tacc += m;
        if (tacc >= NLON) tacc -= NLON;
#pragma unroll
        for (int b = 0; b < 8; ++b) {
            float2 e = exo[b * 362 + n];
            aRe[b] += fc * e.x;
            if (CPLX) aIm[b] += fs * e.y;
        }
    }

    if (valid) {
        float4* __restrict__ xt4 = (float4*)xt;
        if (CPLX) {
            int base = (m_local * NLAT + k) * 4;
#pragma unroll
            for (int q = 0; q < 4; ++q)
                xt4[base + q] = make_float4(aRe[2*q], aIm[2*q], aRe[2*q+1], aIm[2*q+1]);
        } else {
            int base = (m_local * NLAT + k) * 2;
            xt4[base + 0] = make_float4(aRe[0], aRe[1], aRe[2], aRe[3]);
            xt4[base + 1] = make_float4(aRe[4], aRe[5], aRe[6], aRe[7]);
        }
    }
}

// ---------------- kernel 2: triangular contraction (unchanged) ----------------
template<int CPLX>
__global__ __launch_bounds__(256) void k_contract(const float* __restrict__ W,
                                                  const float* __restrict__ xt,
                                                  float* __restrict__ out,
                                                  int mb) {
    const int lt   = blockIdx.x;
    const int mloc = blockIdx.y;
    const int m    = mb + mloc;
    const int l0   = lt * 32;
    const int tid  = threadIdx.x;

    if (l0 + 31 < m) {
        int l = l0 + (tid >> 3), bc = tid & 7;
        int idx = (bc * LMAX + l) * MMAX + m;
        if (CPLX) ((float2*)out)[idx] = make_float2(0.f, 0.f);
        else      out[idx] = 0.f;
        return;
    }

    const int kk = tid & 31, lq = tid >> 5;
    const int lb = l0 + lq * 4;

    int lr[4];
#pragma unroll
    for (int j = 0; j < 4; ++j) lr[j] = (lb + j < LMAX) ? (lb + j) : (LMAX - 1);

    const float* __restrict__ Wm = W + (size_t)m * (LMAX * NLAT);
    const float4* __restrict__ xt4 = (const float4*)xt;
    constexpr int NX = CPLX ? 4 : 2;
    constexpr int NV = CPLX ? 64 : 32;

    float v[NV];
#pragma unroll
    for (int i = 0; i < NV; ++i) v[i] = 0.f;

#define CLOAD(T, WV, XV) { \
    int kq = (T) * 32 + kk; \
    int kc = (kq < NLAT) ? kq : (NLAT - 1); \
    _Pragma("unroll") \
    for (int j = 0; j < 4; ++j) WV[j] = Wm[lr[j] * NLAT + kc]; \
    int xb = (mloc * NLAT + kc) * NX; \
    _Pragma("unroll") \
    for (int q = 0; q < NX; ++q) XV[q] = xt4[xb + q]; \
    if (kq >= NLAT) { WV[0] = WV[1] = WV[2] = WV[3] = 0.f; } }

    float  wc[4]; float4 xc[NX];
    CLOAD(0, wc, xc)
#pragma unroll
    for (int t = 0; t < 12; ++t) {
        float  wn[4]; float4 xn[NX];
        if (t < 11) CLOAD(t + 1, wn, xn)
#pragma unroll
        for (int j = 0; j < 4; ++j) {
            float wj = wc[j];
            if (CPLX) {
#pragma unroll
                for (int q = 0; q < 4; ++q) {
                    v[j*16 + (2*q  )*2 + 0] += wj * xc[q].x;
                    v[j*16 + (2*q  )*2 + 1] += wj * xc[q].y;
                    v[j*16 + (2*q+1)*2 + 0] += wj * xc[q].z;
                    v[j*16 + (2*q+1)*2 + 1] += wj * xc[q].w;
                }
            } else {
                v[j*8 + 0] += wj * xc[0].x;  v[j*8 + 1] += wj * xc[0].y;
                v[j*8 + 2] += wj * xc[0].z;  v[j*8 + 3] += wj * xc[0].w;
                v[j*8 + 4] += wj * xc[1].x;  v[j*8 + 5] += wj * xc[1].y;
                v[j*8 + 6] += wj * xc[1].z;  v[j*8 + 7] += wj * xc[1].w;
            }
        }
        if (t < 11) {
#pragma unroll
            for (int j = 0; j < 4; ++j) wc[j] = wn[j];
#pragma unroll
            for (int q = 0; q < NX; ++q) xc[q] = xn[q];
        }
    }
#undef CLOAD

#define RSTEP(MASK, CNT) { const bool hi = (kk & MASK) != 0; \
    _Pragma("unroll") \
    for (int i = 0; i < CNT; ++i) { \
        float keep = hi ? v[i + CNT] : v[i]; \
        float send = hi ? v[i] : v[i + CNT]; \
        v[i] = keep + __shfl_xor(send, MASK); } }
    if (CPLX) {
        RSTEP(16, 32) RSTEP(8, 16) RSTEP(4, 8) RSTEP(2, 4) RSTEP(1, 2)
    } else {
        RSTEP(16, 16) RSTEP(8, 8) RSTEP(4, 4) RSTEP(2, 2) RSTEP(1, 1)
    }
#undef RSTEP

    int j  = kk >> 3;
    int bc = kk & 7;
    int l  = l0 + lq * 4 + j;
    if (l >= LMAX) return;
    int idx = (bc * LMAX + l) * MMAX + m;
    if (CPLX) {
        float2 r = make_float2(v[0], v[1]);
        if (l < m) r = make_float2(0.f, 0.f);
        ((float2*)out)[idx] = r;
    } else {
        float r = (l < m) ? 0.f : v[0];
        out[idx] = r;
    }
}

extern "C" void kernel_launch(void* const* d_in, const int* in_sizes, int n_in,
                              void* d_out, int out_size, void* d_ws, size_t ws_size,
                              hipStream_t stream) {
    const float* x = (const float*)d_in[0];
    const float* W = (const float*)d_in[1];
    float* ws = (float*)d_ws;

    const int n_complex = 8 * LMAX * MMAX;            // 1,039,680
    const int cplx = (out_size >= 2 * n_complex) ? 1 : 0;

    if (!cplx) {
        // main path: 4 Xt quarters + final Xt + real table
        const size_t need = ((size_t)5 * XTQ_FLOATS + TAB_R_FLOATS) * sizeof(float);
        if (ws_size >= need) {
            float* q0 = ws;
            float* q1 = ws + (size_t)XTQ_FLOATS;
            float* q2 = ws + (size_t)2 * XTQ_FLOATS;
            float* q3 = ws + (size_t)3 * XTQ_FLOATS;
            float* xt = ws + (size_t)4 * XTQ_FLOATS;
            float* tc = ws + (size_t)5 * XTQ_FLOATS;
            k_tables_r<<<dim3((TAB_R_FLOATS + 255) / 256), dim3(256), 0, stream>>>(tc);
            k_dft_r<<<dim3(181, 4), dim3(256), 0, stream>>>(x, tc, q0);
            k_reduce<<<dim3((XTQ_FLOATS / 4 + 255) / 256), dim3(256), 0, stream>>>(
                (const float4*)q0, (const float4*)q1, (const float4*)q2,
                (const float4*)q3, (float4*)xt);
            k_contract<0><<<dim3(12, MMAX), dim3(256), 0, stream>>>(W, xt, (float*)d_out, 0);
            return;
        }
    }

    // hedge / fallback: legacy sincosf path (chunked if ws small)
    const int xs_per_mk = cplx ? 16 : 8;
    const size_t per_m_bytes = (size_t)NLAT * xs_per_mk * sizeof(float);
    int CM = (int)(ws_size / per_m_bytes);
    if (CM > MMAX) CM = MMAX;
    if (CM < 1)    CM = 1;
    for (int mbase = 0; mbase < MMAX; mbase += CM) {
        int mc = MMAX - mbase;
        if (mc > CM) mc = CM;
        if (cplx) {
            k_dft_leg<1><<<dim3(NLAT, (mc + 191) / 192), dim3(192), 0, stream>>>(
                x, ws, mbase, mc);
            k_contract<1><<<dim3(12, mc), dim3(256), 0, stream>>>(W, ws, (float*)d_out, mbase);
        } else {
            k_dft_leg<0><<<dim3(NLAT, (mc + 191) / 192), dim3(192), 0, stream>>>(
                x, ws, mbase, mc);
            k_contract<0><<<dim3(12, mc), dim3(256), 0, stream>>>(W, ws, (float*)d_out, mbase);
        }
    }
}

// Round 8
// 67.573 us; speedup vs baseline: 1.4645x; 1.4645x over previous
//
#include <hip/hip_runtime.h>

#define NLAT 361
#define NLON 720
#define LMAX 360
#define MMAX 361

#define NS   6                        // n-split across blocks
#define QN   61                       // ceil(361/6); last quarter = 56
#define TT_STRIDE 384                 // table row stride (m-contiguous), cols 361..383 = 0
#define TT_FLOATS (NLAT * TT_STRIDE)  // 138,624
#define XTQ_FLOATS (MMAX * NLAT * 8)  // 1,042,568 per quarter (real Xt [m][k][8ch])

static constexpr float kAngF = 8.72664625997164788e-3f;  // 2*pi/720

// ---------------- kernel 0: transposed trig table Tt[n][m] ----------------
__global__ __launch_bounds__(256) void k_tables_t(float* __restrict__ tt) {
    int i = blockIdx.x * 256 + threadIdx.x;
    if (i >= TT_FLOATS) return;
    int n  = i / TT_STRIDE;
    int mc = i - n * TT_STRIDE;
    float v = 0.f;
    if (mc <= 360) {
        int t = (n * mc) % NLON;
        float sn, cs;
        __sincosf((float)t * kAngF, &sn, &cs);
        float w = (n == 360) ? 0.5f : 1.0f;
        v = w * kAngF * cs;
    }
    tt[i] = v;
}

// ---------------- kernel 1: folded real DFT ----------------
// Xq[nq][m,k,ch] = sum_{n in slice nq} Tt[n][m] * xe[n,k,ch]
// grid (181 k-pairs, NS n-slices), block 256 = 2 kslots x 128 m-lanes (3 m each).
// Coalesced table loads (lane<->m); fold reads x directly (no big staging).
__global__ __launch_bounds__(256) void k_dft2(const float* __restrict__ x,
                                              const float* __restrict__ tt,
                                              float* __restrict__ xtq) {
    const int bx  = blockIdx.x;      // k pair: k = 2*bx + ks
    const int nq  = blockIdx.y;      // n slice
    const int tid = threadIdx.x;
    const int ks  = tid >> 7;        // 0/1
    const int ml  = tid & 127;       // m lane
    const int n0  = nq * QN;
    const int cnt = min(QN, NLAT - n0);

    __shared__ __align__(16) float xe[2][QN][8];

    // fold: idx = (s*8+ch)*QN + nn  (nn fastest -> coalesced x reads, fwd & mirror)
    for (int j = tid; j < 2 * 8 * QN; j += 256) {
        int s  = j / (8 * QN);
        int r  = j - s * (8 * QN);
        int ch = r / QN;
        int nn = r - ch * QN;
        int n  = n0 + nn;
        int k  = bx * 2 + s;
        float v = 0.f;
        if (n <= 360 && k <= 360) {
            const float* __restrict__ row = x + ((size_t)ch * NLAT + k) * NLON;
            float a = row[n];
            float b = (n == 0) ? 0.f : row[NLON - n];   // n=360: row[360] -> 2x, tab w=0.5
            v = a + b;
        }
        xe[s][nn][ch] = v;
    }
    __syncthreads();

    float acc[3][8];
#pragma unroll
    for (int q = 0; q < 3; ++q)
#pragma unroll
        for (int b = 0; b < 8; ++b) acc[q][b] = 0.f;

    const float* __restrict__ tr0 = tt + (size_t)n0 * TT_STRIDE;
    float f0 = tr0[ml], f1 = tr0[ml + 128], f2 = tr0[ml + 256];
    for (int nn = 0; nn < cnt; ++nn) {
        float g0 = 0.f, g1 = 0.f, g2 = 0.f;
        if (nn + 1 < cnt) {
            const float* __restrict__ trn = tr0 + (nn + 1) * TT_STRIDE;
            g0 = trn[ml]; g1 = trn[ml + 128]; g2 = trn[ml + 256];
        }
        float4 e0 = *(const float4*)&xe[ks][nn][0];
        float4 e1 = *(const float4*)&xe[ks][nn][4];
        acc[0][0] += f0 * e0.x;  acc[0][1] += f0 * e0.y;
        acc[0][2] += f0 * e0.z;  acc[0][3] += f0 * e0.w;
        acc[0][4] += f0 * e1.x;  acc[0][5] += f0 * e1.y;
        acc[0][6] += f0 * e1.z;  acc[0][7] += f0 * e1.w;
        acc[1][0] += f1 * e0.x;  acc[1][1] += f1 * e0.y;
        acc[1][2] += f1 * e0.z;  acc[1][3] += f1 * e0.w;
        acc[1][4] += f1 * e1.x;  acc[1][5] += f1 * e1.y;
        acc[1][6] += f1 * e1.z;  acc[1][7] += f1 * e1.w;
        acc[2][0] += f2 * e0.x;  acc[2][1] += f2 * e0.y;
        acc[2][2] += f2 * e0.z;  acc[2][3] += f2 * e0.w;
        acc[2][4] += f2 * e1.x;  acc[2][5] += f2 * e1.y;
        acc[2][6] += f2 * e1.z;  acc[2][7] += f2 * e1.w;
        f0 = g0; f1 = g1; f2 = g2;
    }

    const int k = bx * 2 + ks;
    if (k <= 360) {
        float4* __restrict__ o4 = (float4*)(xtq + (size_t)nq * XTQ_FLOATS);
        const int m0 = ml, m1 = ml + 128, m2 = ml + 256;
        int b0 = (m0 * NLAT + k) * 2;
        o4[b0]     = make_float4(acc[0][0], acc[0][1], acc[0][2], acc[0][3]);
        o4[b0 + 1] = make_float4(acc[0][4], acc[0][5], acc[0][6], acc[0][7]);
        int b1 = (m1 * NLAT + k) * 2;
        o4[b1]     = make_float4(acc[1][0], acc[1][1], acc[1][2], acc[1][3]);
        o4[b1 + 1] = make_float4(acc[1][4], acc[1][5], acc[1][6], acc[1][7]);
        if (m2 <= 360) {
            int b2 = (m2 * NLAT + k) * 2;
            o4[b2]     = make_float4(acc[2][0], acc[2][1], acc[2][2], acc[2][3]);
            o4[b2 + 1] = make_float4(acc[2][4], acc[2][5], acc[2][6], acc[2][7]);
        }
    }
}

// ---------------- kernel 1b: sum the NS n-slices ----------------
__global__ __launch_bounds__(256) void k_reduce6(const float* __restrict__ q,
                                                 float4* __restrict__ o) {
    int i = blockIdx.x * 256 + threadIdx.x;
    if (i >= XTQ_FLOATS / 4) return;
    const float4* q4 = (const float4*)q;
    float4 s = q4[i];
#pragma unroll
    for (int u = 1; u < NS; ++u) {
        float4 a = q4[i + (size_t)u * (XTQ_FLOATS / 4)];
        s.x += a.x; s.y += a.y; s.z += a.z; s.w += a.w;
    }
    o[i] = s;
}

// ---------------- legacy folded DFT (cplx hedge / small-ws fallback) ----------------
template<int CPLX>
__global__ __launch_bounds__(192) void k_dft_leg(const float* __restrict__ x,
                                                 float* __restrict__ xt,
                                                 int mb, int mc) {
    const int k    = blockIdx.x;
    const int half = blockIdx.y;
    const int tid  = threadIdx.x;

    __shared__ __align__(16) float  xr[8 * 724];
    __shared__ __align__(16) float2 exo[8 * 362];

    {
        const float4* __restrict__ x4 = (const float4*)x;
        for (int j = tid; j < 8 * 180; j += 192) {
            int b = j / 180, q = j - b * 180;
            ((float4*)&xr[b * 724])[q] = x4[(b * NLAT + k) * 180 + q];
        }
        if (tid < 8) ((float4*)&xr[tid * 724])[180] = make_float4(0.f, 0.f, 0.f, 0.f);
    }
    __syncthreads();

    for (int j = tid; j < 8 * NLAT; j += 192) {
        int b = j / NLAT, n = j - b * NLAT;
        float xa  = xr[b * 724 + n];
        float xbv = xr[b * 724 + (NLON - n)];
        exo[b * 362 + n] = make_float2(xa + xbv, xa - xbv);
    }
    __syncthreads();

    const int  m_local = half * 192 + tid;
    const bool valid   = (m_local < mc);
    const int  m       = mb + (valid ? m_local : 0);

    float aRe[8], aIm[8];
#pragma unroll
    for (int b = 0; b < 8; ++b) { aRe[b] = 0.f; aIm[b] = 0.f; }

    int tacc = 0;
    for (int n = 0; n < NLAT; ++n) {
        float sn, cs;
        __sincosf((float)tacc * kAngF, &sn, &cs);
        float wgt = (n == 360) ? 0.5f : 1.0f;
        float fc = wgt * kAngF * cs;
        float fs = -wgt * kAngF * sn;
        tacc += m;
        if (tacc >= NLON) tacc -= NLON;
#pragma unroll
        for (int b = 0; b < 8; ++b) {
            float2 e = exo[b * 362 + n];
            aRe[b] += fc * e.x;
            if (CPLX) aIm[b] += fs * e.y;
        }
    }

    if (valid) {
        float4* __restrict__ xt4 = (float4*)xt;
        if (CPLX) {
            int base = (m_local * NLAT + k) * 4;
#pragma unroll
            for (int q = 0; q < 4; ++q)
                xt4[base + q] = make_float4(aRe[2*q], aIm[2*q], aRe[2*q+1], aIm[2*q+1]);
        } else {
            int base = (m_local * NLAT + k) * 2;
            xt4[base + 0] = make_float4(aRe[0], aRe[1], aRe[2], aRe[3]);
            xt4[base + 1] = make_float4(aRe[4], aRe[5], aRe[6], aRe[7]);
        }
    }
}

// ---------------- kernel 2: triangular contraction (unchanged) ----------------
template<int CPLX>
__global__ __launch_bounds__(256) void k_contract(const float* __restrict__ W,
                                                  const float* __restrict__ xt,
                                                  float* __restrict__ out,
                                                  int mb) {
    const int lt   = blockIdx.x;
    const int mloc = blockIdx.y;
    const int m    = mb + mloc;
    const int l0   = lt * 32;
    const int tid  = threadIdx.x;

    if (l0 + 31 < m) {
        int l = l0 + (tid >> 3), bc = tid & 7;
        int idx = (bc * LMAX + l) * MMAX + m;
        if (CPLX) ((float2*)out)[idx] = make_float2(0.f, 0.f);
        else      out[idx] = 0.f;
        return;
    }

    const int kk = tid & 31, lq = tid >> 5;
    const int lb = l0 + lq * 4;

    int lr[4];
#pragma unroll
    for (int j = 0; j < 4; ++j) lr[j] = (lb + j < LMAX) ? (lb + j) : (LMAX - 1);

    const float* __restrict__ Wm = W + (size_t)m * (LMAX * NLAT);
    const float4* __restrict__ xt4 = (const float4*)xt;
    constexpr int NX = CPLX ? 4 : 2;
    constexpr int NV = CPLX ? 64 : 32;

    float v[NV];
#pragma unroll
    for (int i = 0; i < NV; ++i) v[i] = 0.f;

#define CLOAD(T, WV, XV) { \
    int kq = (T) * 32 + kk; \
    int kc = (kq < NLAT) ? kq : (NLAT - 1); \
    _Pragma("unroll") \
    for (int j = 0; j < 4; ++j) WV[j] = Wm[lr[j] * NLAT + kc]; \
    int xb = (mloc * NLAT + kc) * NX; \
    _Pragma("unroll") \
    for (int q = 0; q < NX; ++q) XV[q] = xt4[xb + q]; \
    if (kq >= NLAT) { WV[0] = WV[1] = WV[2] = WV[3] = 0.f; } }

    float  wc[4]; float4 xc[NX];
    CLOAD(0, wc, xc)
#pragma unroll
    for (int t = 0; t < 12; ++t) {
        float  wn[4]; float4 xn[NX];
        if (t < 11) CLOAD(t + 1, wn, xn)
#pragma unroll
        for (int j = 0; j < 4; ++j) {
            float wj = wc[j];
            if (CPLX) {
#pragma unroll
                for (int q = 0; q < 4; ++q) {
                    v[j*16 + (2*q  )*2 + 0] += wj * xc[q].x;
                    v[j*16 + (2*q  )*2 + 1] += wj * xc[q].y;
                    v[j*16 + (2*q+1)*2 + 0] += wj * xc[q].z;
                    v[j*16 + (2*q+1)*2 + 1] += wj * xc[q].w;
                }
            } else {
                v[j*8 + 0] += wj * xc[0].x;  v[j*8 + 1] += wj * xc[0].y;
                v[j*8 + 2] += wj * xc[0].z;  v[j*8 + 3] += wj * xc[0].w;
                v[j*8 + 4] += wj * xc[1].x;  v[j*8 + 5] += wj * xc[1].y;
                v[j*8 + 6] += wj * xc[1].z;  v[j*8 + 7] += wj * xc[1].w;
            }
        }
        if (t < 11) {
#pragma unroll
            for (int j = 0; j < 4; ++j) wc[j] = wn[j];
#pragma unroll
            for (int q = 0; q < NX; ++q) xc[q] = xn[q];
        }
    }
#undef CLOAD

#define RSTEP(MASK, CNT) { const bool hi = (kk & MASK) != 0; \
    _Pragma("unroll") \
    for (int i = 0; i < CNT; ++i) { \
        float keep = hi ? v[i + CNT] : v[i]; \
        float send = hi ? v[i] : v[i + CNT]; \
        v[i] = keep + __shfl_xor(send, MASK); } }
    if (CPLX) {
        RSTEP(16, 32) RSTEP(8, 16) RSTEP(4, 8) RSTEP(2, 4) RSTEP(1, 2)
    } else {
        RSTEP(16, 16) RSTEP(8, 8) RSTEP(4, 4) RSTEP(2, 2) RSTEP(1, 1)
    }
#undef RSTEP

    int j  = kk >> 3;
    int bc = kk & 7;
    int l  = l0 + lq * 4 + j;
    if (l >= LMAX) return;
    int idx = (bc * LMAX + l) * MMAX + m;
    if (CPLX) {
        float2 r = make_float2(v[0], v[1]);
        if (l < m) r = make_float2(0.f, 0.f);
        ((float2*)out)[idx] = r;
    } else {
        float r = (l < m) ? 0.f : v[0];
        out[idx] = r;
    }
}

extern "C" void kernel_launch(void* const* d_in, const int* in_sizes, int n_in,
                              void* d_out, int out_size, void* d_ws, size_t ws_size,
                              hipStream_t stream) {
    const float* x = (const float*)d_in[0];
    const float* W = (const float*)d_in[1];
    float* ws = (float*)d_ws;

    const int n_complex = 8 * LMAX * MMAX;            // 1,039,680
    const int cplx = (out_size >= 2 * n_complex) ? 1 : 0;

    if (!cplx) {
        // main path: NS slice buffers + final Xt + transposed table
        const size_t need = ((size_t)(NS + 1) * XTQ_FLOATS + TT_FLOATS) * sizeof(float);
        if (ws_size >= need) {
            float* q  = ws;                                    // NS slice buffers
            float* xt = ws + (size_t)NS * XTQ_FLOATS;
            float* tt = ws + (size_t)(NS + 1) * XTQ_FLOATS;
            k_tables_t<<<dim3((TT_FLOATS + 255) / 256), dim3(256), 0, stream>>>(tt);
            k_dft2<<<dim3(181, NS), dim3(256), 0, stream>>>(x, tt, q);
            k_reduce6<<<dim3((XTQ_FLOATS / 4 + 255) / 256), dim3(256), 0, stream>>>(
                q, (float4*)xt);
            k_contract<0><<<dim3(12, MMAX), dim3(256), 0, stream>>>(W, xt, (float*)d_out, 0);
            return;
        }
    }

    // hedge / fallback: legacy sincosf path (chunked if ws small)
    const int xs_per_mk = cplx ? 16 : 8;
    const size_t per_m_bytes = (size_t)NLAT * xs_per_mk * sizeof(float);
    int CM = (int)(ws_size / per_m_bytes);
    if (CM > MMAX) CM = MMAX;
    if (CM < 1)    CM = 1;
    for (int mbase = 0; mbase < MMAX; mbase += CM) {
        int mc = MMAX - mbase;
        if (mc > CM) mc = CM;
        if (cplx) {
            k_dft_leg<1><<<dim3(NLAT, (mc + 191) / 192), dim3(192), 0, stream>>>(
                x, ws, mbase, mc);
            k_contract<1><<<dim3(12, mc), dim3(256), 0, stream>>>(W, ws, (float*)d_out, mbase);
        } else {
            k_dft_leg<0><<<dim3(NLAT, (mc + 191) / 192), dim3(192), 0, stream>>>(
                x, ws, mbase, mc);
            k_contract<0><<<dim3(12, mc), dim3(256), 0, stream>>>(W, ws, (float*)d_out, mbase);
        }
    }
}

// Round 10
// 65.828 us; speedup vs baseline: 1.5033x; 1.0265x over previous
//
#include <hip/hip_runtime.h>

#define NLAT 361
#define NLON 720
#define LMAX 360
#define MMAX 361

#define NS   6                        // n-split across blocks
#define QN   61                       // slice width: 6*61 = 366 >= 361
#define NN   64                       // padded main-loop iterations per slice
#define TT_ROWS 372                   // table rows (n), zero-padded past 360
#define TT_STRIDE 384                 // table row stride (m-contiguous), cols 361..383 = 0
#define TT_FLOATS (TT_ROWS * TT_STRIDE)   // 142,848
#define XTQ_FLOATS (MMAX * NLAT * 8)  // 1,042,568 per slice (real Xt [m][k][8ch])

static constexpr float kAngF = 8.72664625997164788e-3f;  // 2*pi/720

// ---------------- kernel 0: transposed trig table Tt[n][m] ----------------
__global__ __launch_bounds__(256) void k_tables_t(float* __restrict__ tt) {
    int i = blockIdx.x * 256 + threadIdx.x;
    if (i >= TT_FLOATS) return;
    int n  = i / TT_STRIDE;
    int mc = i - n * TT_STRIDE;
    float v = 0.f;
    if (mc <= 360 && n <= 360) {
        int t = (n * mc) % NLON;
        float sn, cs;
        __sincosf((float)t * kAngF, &sn, &cs);
        float w = (n == 360) ? 0.5f : 1.0f;
        v = w * kAngF * cs;
    }
    tt[i] = v;
}

// ---------------- kernel 1: folded real DFT, 4-deep pipelined ----------------
// Xq[nq][m,k,ch] = sum_{n in slice nq} Tt[n][m] * xe[n,k,ch]
// grid (181 k-pairs, NS slices), block 256 = 2 kslots x 128 m-lanes (3 m each).
__global__ __launch_bounds__(256) void k_dft3(const float* __restrict__ x,
                                              const float* __restrict__ tt,
                                              float* __restrict__ xtq) {
    const int bx  = blockIdx.x;      // k pair: k = 2*bx + ks
    const int nq  = blockIdx.y;      // n slice
    const int tid = threadIdx.x;
    const int ks  = tid >> 7;        // 0/1
    const int ml  = tid & 127;       // m lane
    const int n0  = nq * QN;

    __shared__ __align__(16) float xe[2][NN][8];

    // fold: xe[s][nn][ch] = x[n] + x[720-n]; zero outside THIS slice's range
    // (nn < QN guard: rows 61..63 are pure padding -> 0, keeps slices disjoint)
    for (int j = tid; j < 2 * 8 * NN; j += 256) {
        int s  = j / (8 * NN);
        int r  = j - s * (8 * NN);
        int ch = r / NN;
        int nn = r - ch * NN;
        int n  = n0 + nn;
        int k  = bx * 2 + s;
        float v = 0.f;
        if (nn < QN && n <= 360 && k <= 360) {
            const float* __restrict__ row = x + ((size_t)ch * NLAT + k) * NLON;
            float a = row[n];
            float b = (n == 0) ? 0.f : row[NLON - n];   // n=360 doubles; table w=0.5
            v = a + b;
        }
        xe[s][nn][ch] = v;
    }
    __syncthreads();

    float acc[3][8];
#pragma unroll
    for (int q = 0; q < 3; ++q)
#pragma unroll
        for (int b = 0; b < 8; ++b) acc[q][b] = 0.f;

    const float* __restrict__ tr = tt + (size_t)n0 * TT_STRIDE + ml;

    float fa[4][3];
#pragma unroll
    for (int d = 0; d < 4; ++d) {
        const float* __restrict__ t0 = tr + d * TT_STRIDE;
        fa[d][0] = t0[0]; fa[d][1] = t0[128]; fa[d][2] = t0[256];
    }

    for (int g = 0; g < NN / 4; ++g) {
        float fb[4][3];
        if (g < NN / 4 - 1) {
#pragma unroll
            for (int d = 0; d < 4; ++d) {
                const float* __restrict__ tn = tr + (4 * g + 4 + d) * TT_STRIDE;
                fb[d][0] = tn[0]; fb[d][1] = tn[128]; fb[d][2] = tn[256];
            }
        }
#pragma unroll
        for (int d = 0; d < 4; ++d) {
            float4 e0 = *(const float4*)&xe[ks][4 * g + d][0];
            float4 e1 = *(const float4*)&xe[ks][4 * g + d][4];
            float f0 = fa[d][0], f1 = fa[d][1], f2 = fa[d][2];
            acc[0][0] += f0 * e0.x;  acc[0][1] += f0 * e0.y;
            acc[0][2] += f0 * e0.z;  acc[0][3] += f0 * e0.w;
            acc[0][4] += f0 * e1.x;  acc[0][5] += f0 * e1.y;
            acc[0][6] += f0 * e1.z;  acc[0][7] += f0 * e1.w;
            acc[1][0] += f1 * e0.x;  acc[1][1] += f1 * e0.y;
            acc[1][2] += f1 * e0.z;  acc[1][3] += f1 * e0.w;
            acc[1][4] += f1 * e1.x;  acc[1][5] += f1 * e1.y;
            acc[1][6] += f1 * e1.z;  acc[1][7] += f1 * e1.w;
            acc[2][0] += f2 * e0.x;  acc[2][1] += f2 * e0.y;
            acc[2][2] += f2 * e0.z;  acc[2][3] += f2 * e0.w;
            acc[2][4] += f2 * e1.x;  acc[2][5] += f2 * e1.y;
            acc[2][6] += f2 * e1.z;  acc[2][7] += f2 * e1.w;
        }
        if (g < NN / 4 - 1) {
#pragma unroll
            for (int d = 0; d < 4; ++d) {
                fa[d][0] = fb[d][0]; fa[d][1] = fb[d][1]; fa[d][2] = fb[d][2];
            }
        }
    }

    const int k = bx * 2 + ks;
    if (k <= 360) {
        float4* __restrict__ o4 = (float4*)(xtq + (size_t)nq * XTQ_FLOATS);
        const int m0 = ml, m1 = ml + 128, m2 = ml + 256;
        int b0 = (m0 * NLAT + k) * 2;
        o4[b0]     = make_float4(acc[0][0], acc[0][1], acc[0][2], acc[0][3]);
        o4[b0 + 1] = make_float4(acc[0][4], acc[0][5], acc[0][6], acc[0][7]);
        int b1 = (m1 * NLAT + k) * 2;
        o4[b1]     = make_float4(acc[1][0], acc[1][1], acc[1][2], acc[1][3]);
        o4[b1 + 1] = make_float4(acc[1][4], acc[1][5], acc[1][6], acc[1][7]);
        if (m2 <= 360) {
            int b2 = (m2 * NLAT + k) * 2;
            o4[b2]     = make_float4(acc[2][0], acc[2][1], acc[2][2], acc[2][3]);
            o4[b2 + 1] = make_float4(acc[2][4], acc[2][5], acc[2][6], acc[2][7]);
        }
    }
}

// ---------------- kernel 1b: sum the NS n-slices ----------------
__global__ __launch_bounds__(256) void k_reduce6(const float* __restrict__ q,
                                                 float4* __restrict__ o) {
    int i = blockIdx.x * 256 + threadIdx.x;
    if (i >= XTQ_FLOATS / 4) return;
    const float4* q4 = (const float4*)q;
    float4 s = q4[i];
#pragma unroll
    for (int u = 1; u < NS; ++u) {
        float4 a = q4[i + (size_t)u * (XTQ_FLOATS / 4)];
        s.x += a.x; s.y += a.y; s.z += a.z; s.w += a.w;
    }
    o[i] = s;
}

// ---------------- legacy folded DFT (cplx hedge / small-ws fallback) ----------------
template<int CPLX>
__global__ __launch_bounds__(192) void k_dft_leg(const float* __restrict__ x,
                                                 float* __restrict__ xt,
                                                 int mb, int mc) {
    const int k    = blockIdx.x;
    const int half = blockIdx.y;
    const int tid  = threadIdx.x;

    __shared__ __align__(16) float  xr[8 * 724];
    __shared__ __align__(16) float2 exo[8 * 362];

    {
        const float4* __restrict__ x4 = (const float4*)x;
        for (int j = tid; j < 8 * 180; j += 192) {
            int b = j / 180, q = j - b * 180;
            ((float4*)&xr[b * 724])[q] = x4[(b * NLAT + k) * 180 + q];
        }
        if (tid < 8) ((float4*)&xr[tid * 724])[180] = make_float4(0.f, 0.f, 0.f, 0.f);
    }
    __syncthreads();

    for (int j = tid; j < 8 * NLAT; j += 192) {
        int b = j / NLAT, n = j - b * NLAT;
        float xa  = xr[b * 724 + n];
        float xbv = xr[b * 724 + (NLON - n)];
        exo[b * 362 + n] = make_float2(xa + xbv, xa - xbv);
    }
    __syncthreads();

    const int  m_local = half * 192 + tid;
    const bool valid   = (m_local < mc);
    const int  m       = mb + (valid ? m_local : 0);

    float aRe[8], aIm[8];
#pragma unroll
    for (int b = 0; b < 8; ++b) { aRe[b] = 0.f; aIm[b] = 0.f; }

    int tacc = 0;
    for (int n = 0; n < NLAT; ++n) {
        float sn, cs;
        __sincosf((float)tacc * kAngF, &sn, &cs);
        float wgt = (n == 360) ? 0.5f : 1.0f;
        float fc = wgt * kAngF * cs;
        float fs = -wgt * kAngF * sn;
        tacc += m;
        if (tacc >= NLON) tacc -= NLON;
#pragma unroll
        for (int b = 0; b < 8; ++b) {
            float2 e = exo[b * 362 + n];
            aRe[b] += fc * e.x;
            if (CPLX) aIm[b] += fs * e.y;
        }
    }

    if (valid) {
        float4* __restrict__ xt4 = (float4*)xt;
        if (CPLX) {
            int base = (m_local * NLAT + k) * 4;
#pragma unroll
            for (int q = 0; q < 4; ++q)
                xt4[base + q] = make_float4(aRe[2*q], aIm[2*q], aRe[2*q+1], aIm[2*q+1]);
        } else {
            int base = (m_local * NLAT + k) * 2;
            xt4[base + 0] = make_float4(aRe[0], aRe[1], aRe[2], aRe[3]);
            xt4[base + 1] = make_float4(aRe[4], aRe[5], aRe[6], aRe[7]);
        }
    }
}

// ---------------- kernel 2: triangular contraction, 2-deep prefetch ----------------
template<int CPLX>
__global__ __launch_bounds__(256) void k_contract(const float* __restrict__ W,
                                                  const float* __restrict__ xt,
                                                  float* __restrict__ out,
                                                  int mb) {
    const int lt   = blockIdx.x;
    const int mloc = blockIdx.y;
    const int m    = mb + mloc;
    const int l0   = lt * 32;
    const int tid  = threadIdx.x;

    if (l0 + 31 < m) {
        int l = l0 + (tid >> 3), bc = tid & 7;
        int idx = (bc * LMAX + l) * MMAX + m;
        if (CPLX) ((float2*)out)[idx] = make_float2(0.f, 0.f);
        else      out[idx] = 0.f;
        return;
    }

    const int kk = tid & 31, lq = tid >> 5;
    const int lb = l0 + lq * 4;

    // rows with l < m produce discarded outputs -> dedup onto row m (saves HBM)
    int lr[4];
#pragma unroll
    for (int j = 0; j < 4; ++j) {
        int l = lb + j;
        if (l < m)        l = m;
        if (l > LMAX - 1) l = LMAX - 1;
        lr[j] = l;
    }

    const float* __restrict__ Wm = W + (size_t)m * (LMAX * NLAT);
    const float4* __restrict__ xt4 = (const float4*)xt;
    constexpr int NX = CPLX ? 4 : 2;
    constexpr int NV = CPLX ? 64 : 32;

    float v[NV];
#pragma unroll
    for (int i = 0; i < NV; ++i) v[i] = 0.f;

#define CLOAD(T, WV, XV) { \
    int kq = (T) * 32 + kk; \
    int kc = (kq < NLAT) ? kq : (NLAT - 1); \
    _Pragma("unroll") \
    for (int j = 0; j < 4; ++j) WV[j] = Wm[lr[j] * NLAT + kc]; \
    int xb = (mloc * NLAT + kc) * NX; \
    _Pragma("unroll") \
    for (int q = 0; q < NX; ++q) XV[q] = xt4[xb + q]; \
    if (kq >= NLAT) { WV[0] = WV[1] = WV[2] = WV[3] = 0.f; } }

#define CFMA(WV, XV) { \
    _Pragma("unroll") \
    for (int j = 0; j < 4; ++j) { \
        float wj = WV[j]; \
        if (CPLX) { \
            _Pragma("unroll") \
            for (int q = 0; q < 4; ++q) { \
                v[j*16 + (2*q  )*2 + 0] += wj * XV[q].x; \
                v[j*16 + (2*q  )*2 + 1] += wj * XV[q].y; \
                v[j*16 + (2*q+1)*2 + 0] += wj * XV[q].z; \
                v[j*16 + (2*q+1)*2 + 1] += wj * XV[q].w; \
            } \
        } else { \
            v[j*8 + 0] += wj * XV[0].x;  v[j*8 + 1] += wj * XV[0].y; \
            v[j*8 + 2] += wj * XV[0].z;  v[j*8 + 3] += wj * XV[0].w; \
            v[j*8 + 4] += wj * XV[1].x;  v[j*8 + 5] += wj * XV[1].y; \
            v[j*8 + 6] += wj * XV[1].z;  v[j*8 + 7] += wj * XV[1].w; \
        } \
    } }

    float  w0[4], w1[4], wn[4];
    float4 x0[NX], x1[NX], xn[NX];
    CLOAD(0, w0, x0)
    CLOAD(1, w1, x1)
#pragma unroll
    for (int t = 0; t < 12; ++t) {
        if (t < 10) CLOAD(t + 2, wn, xn)
        CFMA(w0, x0)
#pragma unroll
        for (int j = 0; j < 4; ++j) w0[j] = w1[j];
#pragma unroll
        for (int q = 0; q < NX; ++q) x0[q] = x1[q];
        if (t < 10) {
#pragma unroll
            for (int j = 0; j < 4; ++j) w1[j] = wn[j];
#pragma unroll
            for (int q = 0; q < NX; ++q) x1[q] = xn[q];
        }
    }
#undef CLOAD
#undef CFMA

#define RSTEP(MASK, CNT) { const bool hi = (kk & MASK) != 0; \
    _Pragma("unroll") \
    for (int i = 0; i < CNT; ++i) { \
        float keep = hi ? v[i + CNT] : v[i]; \
        float send = hi ? v[i] : v[i + CNT]; \
        v[i] = keep + __shfl_xor(send, MASK); } }
    if (CPLX) {
        RSTEP(16, 32) RSTEP(8, 16) RSTEP(4, 8) RSTEP(2, 4) RSTEP(1, 2)
    } else {
        RSTEP(16, 16) RSTEP(8, 8) RSTEP(4, 4) RSTEP(2, 2) RSTEP(1, 1)
    }
#undef RSTEP

    int j  = kk >> 3;
    int bc = kk & 7;
    int l  = l0 + lq * 4 + j;
    if (l >= LMAX) return;
    int idx = (bc * LMAX + l) * MMAX + m;
    if (CPLX) {
        float2 r = make_float2(v[0], v[1]);
        if (l < m) r = make_float2(0.f, 0.f);
        ((float2*)out)[idx] = r;
    } else {
        float r = (l < m) ? 0.f : v[0];
        out[idx] = r;
    }
}

extern "C" void kernel_launch(void* const* d_in, const int* in_sizes, int n_in,
                              void* d_out, int out_size, void* d_ws, size_t ws_size,
                              hipStream_t stream) {
    const float* x = (const float*)d_in[0];
    const float* W = (const float*)d_in[1];
    float* ws = (float*)d_ws;

    const int n_complex = 8 * LMAX * MMAX;            // 1,039,680
    const int cplx = (out_size >= 2 * n_complex) ? 1 : 0;

    if (!cplx) {
        const size_t need = ((size_t)(NS + 1) * XTQ_FLOATS + TT_FLOATS) * sizeof(float);
        if (ws_size >= need) {
            float* q  = ws;                                    // NS slice buffers
            float* xt = ws + (size_t)NS * XTQ_FLOATS;
            float* tt = ws + (size_t)(NS + 1) * XTQ_FLOATS;
            k_tables_t<<<dim3((TT_FLOATS + 255) / 256), dim3(256), 0, stream>>>(tt);
            k_dft3<<<dim3(181, NS), dim3(256), 0, stream>>>(x, tt, q);
            k_reduce6<<<dim3((XTQ_FLOATS / 4 + 255) / 256), dim3(256), 0, stream>>>(
                q, (float4*)xt);
            k_contract<0><<<dim3(12, MMAX), dim3(256), 0, stream>>>(W, xt, (float*)d_out, 0);
            return;
        }
    }

    // hedge / fallback: legacy sincosf path (chunked if ws small)
    const int xs_per_mk = cplx ? 16 : 8;
    const size_t per_m_bytes = (size_t)NLAT * xs_per_mk * sizeof(float);
    int CM = (int)(ws_size / per_m_bytes);
    if (CM > MMAX) CM = MMAX;
    if (CM < 1)    CM = 1;
    for (int mbase = 0; mbase < MMAX; mbase += CM) {
        int mc = MMAX - mbase;
        if (mc > CM) mc = CM;
        if (cplx) {
            k_dft_leg<1><<<dim3(NLAT, (mc + 191) / 192), dim3(192), 0, stream>>>(
                x, ws, mbase, mc);
            k_contract<1><<<dim3(12, mc), dim3(256), 0, stream>>>(W, ws, (float*)d_out, mbase);
        } else {
            k_dft_leg<0><<<dim3(NLAT, (mc + 191) / 192), dim3(192), 0, stream>>>(
                x, ws, mbase, mc);
            k_contract<0><<<dim3(12, mc), dim3(256), 0, stream>>>(W, ws, (float*)d_out, mbase);
        }
    }
}

// Round 11
// 54.152 us; speedup vs baseline: 1.8274x; 1.2156x over previous
//
#include <hip/hip_runtime.h>

#define NLAT 361
#define NLON 720
#define LMAX 360
#define MMAX 361

#define NS   6                        // n-split across blocks
#define QN   61                       // slice width: 6*61 = 366 >= 361
#define NN   64                       // padded main-loop iterations per slice
#define XTQ_FLOATS (MMAX * NLAT * 8)  // 1,042,568 per slice (real Xt [m][k][8ch])

static constexpr float kAngF = 8.72664625997164788e-3f;  // 2*pi/720

// ---------------- kernel 1: folded real DFT, Chebyshev recurrence ----------------
// Xq[nq][m,k,ch] = sum_{n in slice} cos(n*m*theta) * xe[n,k,ch]   (x theta at end)
// grid (181 k-pairs, NS slices), block 256 = 2 kslots x 128 m-lanes (3 m each).
__global__ __launch_bounds__(256) void k_dft4(const float* __restrict__ x,
                                              float* __restrict__ xtq) {
    const int bx  = blockIdx.x;      // k pair: k = 2*bx + ks
    const int nq  = blockIdx.y;      // n slice
    const int tid = threadIdx.x;
    const int ks  = tid >> 7;        // 0/1
    const int ml  = tid & 127;       // m lane
    const int n0  = nq * QN;

    __shared__ __align__(16) float xe[2][NN][8];

    // fold: xe[s][nn][ch] = x[n] + x[720-n]; zero outside this slice (nn<QN)
    for (int j = tid; j < 2 * 8 * NN; j += 256) {
        int s  = j / (8 * NN);
        int r  = j - s * (8 * NN);
        int ch = r / NN;
        int nn = r - ch * NN;
        int n  = n0 + nn;
        int k  = bx * 2 + s;
        float v = 0.f;
        if (nn < QN && n <= 360 && k <= 360) {
            const float* __restrict__ row = x + ((size_t)ch * NLAT + k) * NLON;
            float a = row[n];
            float b = (n == 0) ? 0.f : row[NLON - n];   // n=360 doubles; 0.5 fixup below
            v = a + b;
        }
        xe[s][nn][ch] = v;
    }
    __syncthreads();

    int mm[3];
    mm[0] = ml; mm[1] = ml + 128;
    const bool m2v = (ml + 256 <= 360);
    mm[2] = m2v ? (ml + 256) : 360;

    // recurrence state: P0 = cos(n0*m*th), P1 = cos((n0+1)*m*th), c2 = 2cos(m*th)
    float P0[3], P1[3], c2[3];
#pragma unroll
    for (int q = 0; q < 3; ++q) {
        int m  = mm[q];
        int t0 = (n0 * m) % NLON;
        int t1 = t0 + m; if (t1 >= NLON) t1 -= NLON;
        P0[q] = cosf((float)t0 * kAngF);
        P1[q] = cosf((float)t1 * kAngF);
        c2[q] = 2.f * cosf((float)m * kAngF);
    }

    float acc[3][8];
#pragma unroll
    for (int q = 0; q < 3; ++q)
#pragma unroll
        for (int b = 0; b < 8; ++b) acc[q][b] = 0.f;

#pragma unroll 4
    for (int nn = 0; nn < NN; ++nn) {
        float4 e0 = *(const float4*)&xe[ks][nn][0];
        float4 e1 = *(const float4*)&xe[ks][nn][4];
#pragma unroll
        for (int q = 0; q < 3; ++q) {
            float f = P0[q];
            acc[q][0] += f * e0.x;  acc[q][1] += f * e0.y;
            acc[q][2] += f * e0.z;  acc[q][3] += f * e0.w;
            acc[q][4] += f * e1.x;  acc[q][5] += f * e1.y;
            acc[q][6] += f * e1.z;  acc[q][7] += f * e1.w;
            float Pn = c2[q] * P1[q] - P0[q];
            P0[q] = P1[q];
            P1[q] = Pn;
        }
    }

    // n=360 term must have weight 0.5 (self-paired fold); it sits in slice NS-1
    // at nn=55 and was accumulated with weight 1 * cos(360*m*th) = (-1)^m.
    if (nq == NS - 1) {
        float4 e0 = *(const float4*)&xe[ks][55][0];
        float4 e1 = *(const float4*)&xe[ks][55][4];
#pragma unroll
        for (int q = 0; q < 3; ++q) {
            float sgn = (mm[q] & 1) ? -1.f : 1.f;
            float h = 0.5f * sgn;
            acc[q][0] -= h * e0.x;  acc[q][1] -= h * e0.y;
            acc[q][2] -= h * e0.z;  acc[q][3] -= h * e0.w;
            acc[q][4] -= h * e1.x;  acc[q][5] -= h * e1.y;
            acc[q][6] -= h * e1.z;  acc[q][7] -= h * e1.w;
        }
    }

#pragma unroll
    for (int q = 0; q < 3; ++q)
#pragma unroll
        for (int b = 0; b < 8; ++b) acc[q][b] *= kAngF;

    const int k = bx * 2 + ks;
    if (k <= 360) {
        float4* __restrict__ o4 = (float4*)(xtq + (size_t)nq * XTQ_FLOATS);
        int b0 = (mm[0] * NLAT + k) * 2;
        o4[b0]     = make_float4(acc[0][0], acc[0][1], acc[0][2], acc[0][3]);
        o4[b0 + 1] = make_float4(acc[0][4], acc[0][5], acc[0][6], acc[0][7]);
        int b1 = (mm[1] * NLAT + k) * 2;
        o4[b1]     = make_float4(acc[1][0], acc[1][1], acc[1][2], acc[1][3]);
        o4[b1 + 1] = make_float4(acc[1][4], acc[1][5], acc[1][6], acc[1][7]);
        if (m2v) {
            int b2 = (mm[2] * NLAT + k) * 2;
            o4[b2]     = make_float4(acc[2][0], acc[2][1], acc[2][2], acc[2][3]);
            o4[b2 + 1] = make_float4(acc[2][4], acc[2][5], acc[2][6], acc[2][7]);
        }
    }
}

// ---------------- kernel 1b: sum the NS n-slices ----------------
__global__ __launch_bounds__(256) void k_reduce6(const float* __restrict__ q,
                                                 float4* __restrict__ o) {
    int i = blockIdx.x * 256 + threadIdx.x;
    if (i >= XTQ_FLOATS / 4) return;
    const float4* q4 = (const float4*)q;
    float4 s = q4[i];
#pragma unroll
    for (int u = 1; u < NS; ++u) {
        float4 a = q4[i + (size_t)u * (XTQ_FLOATS / 4)];
        s.x += a.x; s.y += a.y; s.z += a.z; s.w += a.w;
    }
    o[i] = s;
}

// ---------------- kernel 2: contraction, all-W-upfront registers ----------------
// out[bc,l,m] = sum_k W[m,l,k] * X[k,m]   (zero for l < m), real only.
__global__ __launch_bounds__(256) void k_contract4(const float* __restrict__ W,
                                                   const float* __restrict__ xt,
                                                   float* __restrict__ out) {
    const int lt   = blockIdx.x;
    const int mloc = blockIdx.y;
    const int m    = mloc;
    const int l0   = lt * 32;
    const int tid  = threadIdx.x;

    if (l0 + 31 < m) {
        int l = l0 + (tid >> 3), bc = tid & 7;
        out[(bc * LMAX + l) * MMAX + m] = 0.f;
        return;
    }

    const int kk = tid & 31, lq = tid >> 5;
    const int lb = l0 + lq * 4;

    int lr[4];
#pragma unroll
    for (int j = 0; j < 4; ++j) {
        int l = lb + j;
        if (l < m)        l = m;          // dedup discarded rows onto row m
        if (l > LMAX - 1) l = LMAX - 1;
        lr[j] = l;
    }

    const float* __restrict__ Wm = W + (size_t)m * (LMAX * NLAT);
    const float* __restrict__ r0 = Wm + lr[0] * NLAT + kk;
    const float* __restrict__ r1 = Wm + lr[1] * NLAT + kk;
    const float* __restrict__ r2 = Wm + lr[2] * NLAT + kk;
    const float* __restrict__ r3 = Wm + lr[3] * NLAT + kk;

    // issue ALL W loads upfront (t<11 are compile-time offsets; ~12KB/wave in flight)
    float wv[12][4];
#pragma unroll
    for (int t = 0; t < 11; ++t) {
        wv[t][0] = r0[t * 32];
        wv[t][1] = r1[t * 32];
        wv[t][2] = r2[t * 32];
        wv[t][3] = r3[t * 32];
    }
    {
        int kq = 11 * 32 + kk;
        int kc = (kq <= 360) ? kq : 360;
        wv[11][0] = Wm[lr[0] * NLAT + kc];
        wv[11][1] = Wm[lr[1] * NLAT + kc];
        wv[11][2] = Wm[lr[2] * NLAT + kc];
        wv[11][3] = Wm[lr[3] * NLAT + kc];
        if (kq > 360) { wv[11][0] = wv[11][1] = wv[11][2] = wv[11][3] = 0.f; }
    }

    float v[32];
#pragma unroll
    for (int i = 0; i < 32; ++i) v[i] = 0.f;

    const float4* __restrict__ xt4 = (const float4*)xt;
#pragma unroll
    for (int t = 0; t < 12; ++t) {
        int kq = t * 32 + kk;
        int kc = (kq <= 360) ? kq : 360;
        int xb = (mloc * NLAT + kc) * 2;
        float4 x0 = xt4[xb], x1 = xt4[xb + 1];
#pragma unroll
        for (int j = 0; j < 4; ++j) {
            float wj = wv[t][j];
            v[j*8 + 0] += wj * x0.x;  v[j*8 + 1] += wj * x0.y;
            v[j*8 + 2] += wj * x0.z;  v[j*8 + 3] += wj * x0.w;
            v[j*8 + 4] += wj * x1.x;  v[j*8 + 5] += wj * x1.y;
            v[j*8 + 6] += wj * x1.z;  v[j*8 + 7] += wj * x1.w;
        }
    }

    // split-butterfly over 32 k-lanes; lane kk ends owning output index kk
#define RSTEP(MASK, CNT) { const bool hi = (kk & MASK) != 0; \
    _Pragma("unroll") \
    for (int i = 0; i < CNT; ++i) { \
        float keep = hi ? v[i + CNT] : v[i]; \
        float send = hi ? v[i] : v[i + CNT]; \
        v[i] = keep + __shfl_xor(send, MASK); } }
    RSTEP(16, 16) RSTEP(8, 8) RSTEP(4, 4) RSTEP(2, 2) RSTEP(1, 1)
#undef RSTEP

    int j  = kk >> 3;
    int bc = kk & 7;
    int l  = l0 + lq * 4 + j;
    if (l >= LMAX) return;
    float r = (l < m) ? 0.f : v[0];
    out[(bc * LMAX + l) * MMAX + m] = r;
}

// ---------------- legacy folded DFT (cplx hedge / small-ws fallback) ----------------
template<int CPLX>
__global__ __launch_bounds__(192) void k_dft_leg(const float* __restrict__ x,
                                                 float* __restrict__ xt,
                                                 int mb, int mc) {
    const int k    = blockIdx.x;
    const int half = blockIdx.y;
    const int tid  = threadIdx.x;

    __shared__ __align__(16) float  xr[8 * 724];
    __shared__ __align__(16) float2 exo[8 * 362];

    {
        const float4* __restrict__ x4 = (const float4*)x;
        for (int j = tid; j < 8 * 180; j += 192) {
            int b = j / 180, q = j - b * 180;
            ((float4*)&xr[b * 724])[q] = x4[(b * NLAT + k) * 180 + q];
        }
        if (tid < 8) ((float4*)&xr[tid * 724])[180] = make_float4(0.f, 0.f, 0.f, 0.f);
    }
    __syncthreads();

    for (int j = tid; j < 8 * NLAT; j += 192) {
        int b = j / NLAT, n = j - b * NLAT;
        float xa  = xr[b * 724 + n];
        float xbv = xr[b * 724 + (NLON - n)];
        exo[b * 362 + n] = make_float2(xa + xbv, xa - xbv);
    }
    __syncthreads();

    const int  m_local = half * 192 + tid;
    const bool valid   = (m_local < mc);
    const int  m       = mb + (valid ? m_local : 0);

    float aRe[8], aIm[8];
#pragma unroll
    for (int b = 0; b < 8; ++b) { aRe[b] = 0.f; aIm[b] = 0.f; }

    int tacc = 0;
    for (int n = 0; n < NLAT; ++n) {
        float sn, cs;
        __sincosf((float)tacc * kAngF, &sn, &cs);
        float wgt = (n == 360) ? 0.5f : 1.0f;
        float fc = wgt * kAngF * cs;
        float fs = -wgt * kAngF * sn;
        tacc += m;
        if (tacc >= NLON) tacc -= NLON;
#pragma unroll
        for (int b = 0; b < 8; ++b) {
            float2 e = exo[b * 362 + n];
            aRe[b] += fc * e.x;
            if (CPLX) aIm[b] += fs * e.y;
        }
    }

    if (valid) {
        float4* __restrict__ xt4 = (float4*)xt;
        if (CPLX) {
            int base = (m_local * NLAT + k) * 4;
#pragma unroll
            for (int q = 0; q < 4; ++q)
                xt4[base + q] = make_float4(aRe[2*q], aIm[2*q], aRe[2*q+1], aIm[2*q+1]);
        } else {
            int base = (m_local * NLAT + k) * 2;
            xt4[base + 0] = make_float4(aRe[0], aRe[1], aRe[2], aRe[3]);
            xt4[base + 1] = make_float4(aRe[4], aRe[5], aRe[6], aRe[7]);
        }
    }
}

// ---------------- legacy contraction (fallback only) ----------------
template<int CPLX>
__global__ __launch_bounds__(256) void k_contract_leg(const float* __restrict__ W,
                                                      const float* __restrict__ xt,
                                                      float* __restrict__ out,
                                                      int mb) {
    const int lt   = blockIdx.x;
    const int mloc = blockIdx.y;
    const int m    = mb + mloc;
    const int l0   = lt * 32;
    const int tid  = threadIdx.x;

    if (l0 + 31 < m) {
        int l = l0 + (tid >> 3), bc = tid & 7;
        int idx = (bc * LMAX + l) * MMAX + m;
        if (CPLX) ((float2*)out)[idx] = make_float2(0.f, 0.f);
        else      out[idx] = 0.f;
        return;
    }

    const int kk = tid & 31, lq = tid >> 5;
    const int lb = l0 + lq * 4;

    int lr[4];
#pragma unroll
    for (int j = 0; j < 4; ++j) {
        int l = lb + j;
        if (l < m)        l = m;
        if (l > LMAX - 1) l = LMAX - 1;
        lr[j] = l;
    }

    const float* __restrict__ Wm = W + (size_t)m * (LMAX * NLAT);
    const float4* __restrict__ xt4 = (const float4*)xt;
    constexpr int NX = CPLX ? 4 : 2;
    constexpr int NV = CPLX ? 64 : 32;

    float v[NV];
#pragma unroll
    for (int i = 0; i < NV; ++i) v[i] = 0.f;

#define CLOAD(T, WV, XV) { \
    int kq = (T) * 32 + kk; \
    int kc = (kq < NLAT) ? kq : (NLAT - 1); \
    _Pragma("unroll") \
    for (int j = 0; j < 4; ++j) WV[j] = Wm[lr[j] * NLAT + kc]; \
    int xb = (mloc * NLAT + kc) * NX; \
    _Pragma("unroll") \
    for (int q = 0; q < NX; ++q) XV[q] = xt4[xb + q]; \
    if (kq >= NLAT) { WV[0] = WV[1] = WV[2] = WV[3] = 0.f; } }

#define CFMA(WV, XV) { \
    _Pragma("unroll") \
    for (int j = 0; j < 4; ++j) { \
        float wj = WV[j]; \
        if (CPLX) { \
            _Pragma("unroll") \
            for (int q = 0; q < 4; ++q) { \
                v[j*16 + (2*q  )*2 + 0] += wj * XV[q].x; \
                v[j*16 + (2*q  )*2 + 1] += wj * XV[q].y; \
                v[j*16 + (2*q+1)*2 + 0] += wj * XV[q].z; \
                v[j*16 + (2*q+1)*2 + 1] += wj * XV[q].w; \
            } \
        } else { \
            v[j*8 + 0] += wj * XV[0].x;  v[j*8 + 1] += wj * XV[0].y; \
            v[j*8 + 2] += wj * XV[0].z;  v[j*8 + 3] += wj * XV[0].w; \
            v[j*8 + 4] += wj * XV[1].x;  v[j*8 + 5] += wj * XV[1].y; \
            v[j*8 + 6] += wj * XV[1].z;  v[j*8 + 7] += wj * XV[1].w; \
        } \
    } }

    float  w0[4], w1[4], wn[4];
    float4 x0[NX], x1[NX], xn[NX];
    CLOAD(0, w0, x0)
    CLOAD(1, w1, x1)
#pragma unroll
    for (int t = 0; t < 12; ++t) {
        if (t < 10) CLOAD(t + 2, wn, xn)
        CFMA(w0, x0)
#pragma unroll
        for (int j = 0; j < 4; ++j) w0[j] = w1[j];
#pragma unroll
        for (int q = 0; q < NX; ++q) x0[q] = x1[q];
        if (t < 10) {
#pragma unroll
            for (int j = 0; j < 4; ++j) w1[j] = wn[j];
#pragma unroll
            for (int q = 0; q < NX; ++q) x1[q] = xn[q];
        }
    }
#undef CLOAD
#undef CFMA

#define RSTEP(MASK, CNT) { const bool hi = (kk & MASK) != 0; \
    _Pragma("unroll") \
    for (int i = 0; i < CNT; ++i) { \
        float keep = hi ? v[i + CNT] : v[i]; \
        float send = hi ? v[i] : v[i + CNT]; \
        v[i] = keep + __shfl_xor(send, MASK); } }
    if (CPLX) {
        RSTEP(16, 32) RSTEP(8, 16) RSTEP(4, 8) RSTEP(2, 4) RSTEP(1, 2)
    } else {
        RSTEP(16, 16) RSTEP(8, 8) RSTEP(4, 4) RSTEP(2, 2) RSTEP(1, 1)
    }
#undef RSTEP

    int j  = kk >> 3;
    int bc = kk & 7;
    int l  = l0 + lq * 4 + j;
    if (l >= LMAX) return;
    int idx = (bc * LMAX + l) * MMAX + m;
    if (CPLX) {
        float2 r = make_float2(v[0], v[1]);
        if (l < m) r = make_float2(0.f, 0.f);
        ((float2*)out)[idx] = r;
    } else {
        float r = (l < m) ? 0.f : v[0];
        out[idx] = r;
    }
}

extern "C" void kernel_launch(void* const* d_in, const int* in_sizes, int n_in,
                              void* d_out, int out_size, void* d_ws, size_t ws_size,
                              hipStream_t stream) {
    const float* x = (const float*)d_in[0];
    const float* W = (const float*)d_in[1];
    float* ws = (float*)d_ws;

    const int n_complex = 8 * LMAX * MMAX;            // 1,039,680
    const int cplx = (out_size >= 2 * n_complex) ? 1 : 0;

    if (!cplx) {
        const size_t need = (size_t)(NS + 1) * XTQ_FLOATS * sizeof(float);
        if (ws_size >= need) {
            float* q  = ws;                                    // NS slice buffers
            float* xt = ws + (size_t)NS * XTQ_FLOATS;
            k_dft4<<<dim3(181, NS), dim3(256), 0, stream>>>(x, q);
            k_reduce6<<<dim3((XTQ_FLOATS / 4 + 255) / 256), dim3(256), 0, stream>>>(
                q, (float4*)xt);
            k_contract4<<<dim3(12, MMAX), dim3(256), 0, stream>>>(W, xt, (float*)d_out);
            return;
        }
    }

    // hedge / fallback: legacy sincosf path (chunked if ws small)
    const int xs_per_mk = cplx ? 16 : 8;
    const size_t per_m_bytes = (size_t)NLAT * xs_per_mk * sizeof(float);
    int CM = (int)(ws_size / per_m_bytes);
    if (CM > MMAX) CM = MMAX;
    if (CM < 1)    CM = 1;
    for (int mbase = 0; mbase < MMAX; mbase += CM) {
        int mc = MMAX - mbase;
        if (mc > CM) mc = CM;
        if (cplx) {
            k_dft_leg<1><<<dim3(NLAT, (mc + 191) / 192), dim3(192), 0, stream>>>(
                x, ws, mbase, mc);
            k_contract_leg<1><<<dim3(12, mc), dim3(256), 0, stream>>>(W, ws, (float*)d_out, mbase);
        } else {
            k_dft_leg<0><<<dim3(NLAT, (mc + 191) / 192), dim3(192), 0, stream>>>(
                x, ws, mbase, mc);
            k_contract_leg<0><<<dim3(12, mc), dim3(256), 0, stream>>>(W, ws, (float*)d_out, mbase);
        }
    }
}